// Round 2
// baseline (1014.706 us; speedup 1.0000x reference)
//
#include <hip/hip_runtime.h>
#include <math.h>

// Problem constants (from reference): B=2, T=2048, D_MODEL=1024, H=16, D=64.
#define TSEQ   2048
#define DMODEL 1024
#define NHEADS 16
#define DHEAD  64
#define BATCH  2

// ---------------------------------------------------------------------------
// Kernel 1: fused QKV projection (+RoPE on q,k), fp32, 128x128x16 tile.
// Grid: x = n-tile (24 tiles over N=3072), y = m-tile (32 tiles over M=4096).
// Outputs q,k,v in [B][H][T][D] layout (contiguous per head) in workspace.
// ---------------------------------------------------------------------------
__global__ __launch_bounds__(256) void qkv_rope_kernel(
    const float* __restrict__ x,
    const float* __restrict__ Wq, const float* __restrict__ Wk,
    const float* __restrict__ Wv,
    const float* __restrict__ cosb, const float* __restrict__ sinb,
    float* __restrict__ qo, float* __restrict__ ko, float* __restrict__ vo)
{
    __shared__ float As[16][132];   // As[k][m] (transposed store), pad->132
    __shared__ float Bs[16][132];   // Bs[k][n]

    const int tid = threadIdx.x;
    const int m0  = blockIdx.y * 128;
    const int n0g = blockIdx.x * 128;          // 0..3071
    const int section = n0g >> 10;             // 0=q,1=k,2=v (1024 % 128 == 0)
    const int n0 = n0g & 1023;
    const float* __restrict__ W   = (section == 0) ? Wq : (section == 1) ? Wk : Wv;
    float* __restrict__ out       = (section == 0) ? qo : (section == 1) ? ko : vo;

    // global-load assignments (BK=16): A: 128x16 = 2 float4/thread
    const int arow = tid >> 2;                 // 0..63  (and +64)
    const int ak   = (tid & 3) << 2;           // 0,4,8,12
    // B: 16x128 = 2 float4/thread
    const int brow = tid >> 5;                 // 0..7 (and +8)
    const int bn   = (tid & 31) << 2;          // 0..124

    // compute assignments: rows {rr, rr+64}+i, cols {cc, cc+64}+j
    const int rr = (tid & 15) << 2;
    const int cc = (tid >> 4) << 2;

    float acc[2][2][4][4] = {};

    const float* Aptr0 = x + (size_t)(m0 + arow) * DMODEL + ak;
    const float* Aptr1 = Aptr0 + (size_t)64 * DMODEL;
    const float* Bptr0 = W + (size_t)brow * DMODEL + n0 + bn;
    const float* Bptr1 = Bptr0 + (size_t)8 * DMODEL;

    float4 av0 = *(const float4*)(Aptr0);
    float4 av1 = *(const float4*)(Aptr1);
    float4 bv0 = *(const float4*)(Bptr0);
    float4 bv1 = *(const float4*)(Bptr1);

    for (int k0 = 0; k0 < DMODEL; k0 += 16) {
        __syncthreads();
        As[ak + 0][arow] = av0.x;  As[ak + 1][arow] = av0.y;
        As[ak + 2][arow] = av0.z;  As[ak + 3][arow] = av0.w;
        As[ak + 0][arow + 64] = av1.x;  As[ak + 1][arow + 64] = av1.y;
        As[ak + 2][arow + 64] = av1.z;  As[ak + 3][arow + 64] = av1.w;
        *(float4*)&Bs[brow][bn]     = bv0;
        *(float4*)&Bs[brow + 8][bn] = bv1;
        __syncthreads();
        if (k0 + 16 < DMODEL) {                // prefetch next K-slice
            av0 = *(const float4*)(Aptr0 + k0 + 16);
            av1 = *(const float4*)(Aptr1 + k0 + 16);
            bv0 = *(const float4*)(Bptr0 + (size_t)(k0 + 16) * DMODEL);
            bv1 = *(const float4*)(Bptr1 + (size_t)(k0 + 16) * DMODEL);
        }
        #pragma unroll
        for (int kk = 0; kk < 16; ++kk) {
            float4 a0 = *(const float4*)&As[kk][rr];
            float4 a1 = *(const float4*)&As[kk][rr + 64];
            float4 b0 = *(const float4*)&Bs[kk][cc];
            float4 b1 = *(const float4*)&Bs[kk][cc + 64];
            float ar[2][4] = {{a0.x, a0.y, a0.z, a0.w}, {a1.x, a1.y, a1.z, a1.w}};
            float br[2][4] = {{b0.x, b0.y, b0.z, b0.w}, {b1.x, b1.y, b1.z, b1.w}};
            #pragma unroll
            for (int bi = 0; bi < 2; ++bi)
                #pragma unroll
                for (int i = 0; i < 4; ++i)
                    #pragma unroll
                    for (int bj = 0; bj < 2; ++bj)
                        #pragma unroll
                        for (int jj = 0; jj < 4; ++jj)
                            acc[bi][bj][i][jj] += ar[bi][i] * br[bj][jj];
        }
    }

    // epilogue: RoPE for q,k; store to [B][H][T][D]
    const int b = m0 >> 11;                    // block fully within one batch
    #pragma unroll
    for (int bi = 0; bi < 2; ++bi) {
        #pragma unroll
        for (int i = 0; i < 4; ++i) {
            const int t = (m0 + bi * 64 + rr + i) & (TSEQ - 1);
            #pragma unroll
            for (int bj = 0; bj < 2; ++bj) {
                const int n  = n0 + bj * 64 + cc;   // col within this W, mult of 4
                const int h  = n >> 6;
                const int d0 = n & 63;
                float a0 = acc[bi][bj][i][0], a1 = acc[bi][bj][i][1];
                float a2 = acc[bi][bj][i][2], a3 = acc[bi][bj][i][3];
                float4 r4;
                if (section < 2) {
                    const int p0 = d0 >> 1;         // pair index (even)
                    float c0v = cosb[t * (DHEAD / 2) + p0];
                    float s0v = sinb[t * (DHEAD / 2) + p0];
                    float c1v = cosb[t * (DHEAD / 2) + p0 + 1];
                    float s1v = sinb[t * (DHEAD / 2) + p0 + 1];
                    r4.x = a0 * c0v - a1 * s0v;
                    r4.y = a0 * s0v + a1 * c0v;
                    r4.z = a2 * c1v - a3 * s1v;
                    r4.w = a2 * s1v + a3 * c1v;
                } else {
                    r4 = make_float4(a0, a1, a2, a3);
                }
                *(float4*)&out[(((size_t)b * NHEADS + h) * TSEQ + t) * DHEAD + d0] = r4;
            }
        }
    }
}

// ---------------------------------------------------------------------------
// Kernel 2: causal flash attention, fp32. One block per (64 q-rows, b*h).
// LDS: Q[64][68], K^T[64][68], V[64][68], P[64][68] (pad 68 -> 2-way max = free).
// 256 threads; thread owns 4x4 of S/P and 4x4 of O (rows r0+i, cols c0+j).
// Online softmax; 16-lane shuffle row reductions.
// ---------------------------------------------------------------------------
__global__ __launch_bounds__(256) void attn_kernel(
    const float* __restrict__ qg, const float* __restrict__ kg,
    const float* __restrict__ vg, float* __restrict__ z)
{
    __shared__ float Qs[64][68];
    __shared__ float Kt[64][68];   // Kt[d][c]
    __shared__ float Vs[64][68];   // Vs[c][d]
    __shared__ float Ps[64][68];

    const int tid = threadIdx.x;
    const int qt  = blockIdx.x;
    const int bh  = blockIdx.y;
    const int b   = bh >> 4;
    const int h   = bh & 15;

    const int r0 = (tid >> 4) << 2;    // compute rows
    const int c0 = (tid & 15) << 2;    // compute cols
    const int lr = (tid >> 4) << 2;    // load rows
    const int ld = (tid & 15) << 2;    // load cols (coalesced)

    const float* __restrict__ qh = qg + (size_t)bh * TSEQ * DHEAD;
    const float* __restrict__ kh = kg + (size_t)bh * TSEQ * DHEAD;
    const float* __restrict__ vh = vg + (size_t)bh * TSEQ * DHEAD;

    #pragma unroll
    for (int l = 0; l < 4; ++l)
        *(float4*)&Qs[lr + l][ld] =
            *(const float4*)(qh + (size_t)(qt * 64 + lr + l) * DHEAD + ld);

    float m_i[4], l_i[4], o[4][4];
    #pragma unroll
    for (int i = 0; i < 4; ++i) {
        m_i[i] = -INFINITY;
        l_i[i] = 0.f;
        #pragma unroll
        for (int jj = 0; jj < 4; ++jj) o[i][jj] = 0.f;
    }

    for (int jt = 0; jt <= qt; ++jt) {
        float4 kv4[4], vv4[4];
        #pragma unroll
        for (int l = 0; l < 4; ++l) {
            kv4[l] = *(const float4*)(kh + (size_t)(jt * 64 + lr + l) * DHEAD + ld);
            vv4[l] = *(const float4*)(vh + (size_t)(jt * 64 + lr + l) * DHEAD + ld);
        }
        __syncthreads();   // previous iteration's reads of Kt/Vs complete
        #pragma unroll
        for (int l = 0; l < 4; ++l) {
            Kt[ld + 0][lr + l] = kv4[l].x;
            Kt[ld + 1][lr + l] = kv4[l].y;
            Kt[ld + 2][lr + l] = kv4[l].z;
            Kt[ld + 3][lr + l] = kv4[l].w;
            *(float4*)&Vs[lr + l][ld] = vv4[l];
        }
        __syncthreads();

        // S = Q K^T  (4x4 in regs)
        float s[4][4] = {};
        #pragma unroll 4
        for (int d4 = 0; d4 < DHEAD; d4 += 4) {
            float qa[4][4];
            #pragma unroll
            for (int i = 0; i < 4; ++i) {
                float4 t4 = *(const float4*)&Qs[r0 + i][d4];
                qa[i][0] = t4.x; qa[i][1] = t4.y; qa[i][2] = t4.z; qa[i][3] = t4.w;
            }
            #pragma unroll
            for (int dd = 0; dd < 4; ++dd) {
                float4 kvv = *(const float4*)&Kt[d4 + dd][c0];
                #pragma unroll
                for (int i = 0; i < 4; ++i) {
                    s[i][0] += qa[i][dd] * kvv.x;
                    s[i][1] += qa[i][dd] * kvv.y;
                    s[i][2] += qa[i][dd] * kvv.z;
                    s[i][3] += qa[i][dd] * kvv.w;
                }
            }
        }

        const float scale = 0.125f;         // 1/sqrt(64)
        const bool diag = (jt == qt);
        #pragma unroll
        for (int i = 0; i < 4; ++i)
            #pragma unroll
            for (int jj = 0; jj < 4; ++jj) {
                float sv = s[i][jj] * scale;
                if (diag && (c0 + jj > r0 + i)) sv = -INFINITY;
                s[i][jj] = sv;
            }

        // online softmax
        #pragma unroll
        for (int i = 0; i < 4; ++i) {
            float mr = fmaxf(fmaxf(s[i][0], s[i][1]), fmaxf(s[i][2], s[i][3]));
            #pragma unroll
            for (int off = 1; off < 16; off <<= 1)
                mr = fmaxf(mr, __shfl_xor(mr, off));
            float mnew  = fmaxf(m_i[i], mr);
            float alpha = __expf(m_i[i] - mnew);   // exp(-inf)=0 on first tile
            float p0 = __expf(s[i][0] - mnew);
            float p1 = __expf(s[i][1] - mnew);
            float p2 = __expf(s[i][2] - mnew);
            float p3 = __expf(s[i][3] - mnew);
            float rs = p0 + p1 + p2 + p3;
            #pragma unroll
            for (int off = 1; off < 16; off <<= 1)
                rs += __shfl_xor(rs, off);
            l_i[i] = l_i[i] * alpha + rs;
            m_i[i] = mnew;
            o[i][0] *= alpha; o[i][1] *= alpha; o[i][2] *= alpha; o[i][3] *= alpha;
            *(float4*)&Ps[r0 + i][c0] = make_float4(p0, p1, p2, p3);
        }
        __syncthreads();

        // O += P V  (thread cols c0+j are output dims)
        #pragma unroll 4
        for (int c4 = 0; c4 < 64; c4 += 4) {
            float pa[4][4];
            #pragma unroll
            for (int i = 0; i < 4; ++i) {
                float4 p4 = *(const float4*)&Ps[r0 + i][c4];
                pa[i][0] = p4.x; pa[i][1] = p4.y; pa[i][2] = p4.z; pa[i][3] = p4.w;
            }
            #pragma unroll
            for (int dd = 0; dd < 4; ++dd) {
                float4 vv = *(const float4*)&Vs[c4 + dd][c0];
                #pragma unroll
                for (int i = 0; i < 4; ++i) {
                    o[i][0] += pa[i][dd] * vv.x;
                    o[i][1] += pa[i][dd] * vv.y;
                    o[i][2] += pa[i][dd] * vv.z;
                    o[i][3] += pa[i][dd] * vv.w;
                }
            }
        }
        __syncthreads();
    }

    // epilogue -> z[B][T][H*D]
    #pragma unroll
    for (int i = 0; i < 4; ++i) {
        float inv = 1.0f / l_i[i];
        int t = qt * 64 + r0 + i;
        float4 r4 = make_float4(o[i][0] * inv, o[i][1] * inv,
                                o[i][2] * inv, o[i][3] * inv);
        *(float4*)&z[((size_t)(b * TSEQ + t)) * DMODEL + h * DHEAD + c0] = r4;
    }
}

// ---------------------------------------------------------------------------
// Kernel 3: output projection z @ W_out -> out. fp32 128x128x16 GEMM.
// ---------------------------------------------------------------------------
__global__ __launch_bounds__(256) void out_proj_kernel(
    const float* __restrict__ A, const float* __restrict__ B,
    float* __restrict__ C)
{
    __shared__ float As[16][132];
    __shared__ float Bs[16][132];

    const int tid = threadIdx.x;
    const int m0 = blockIdx.y * 128;
    const int n0 = blockIdx.x * 128;

    const int arow = tid >> 2;
    const int ak   = (tid & 3) << 2;
    const int brow = tid >> 5;
    const int bn   = (tid & 31) << 2;
    const int rr   = (tid & 15) << 2;
    const int cc   = (tid >> 4) << 2;

    float acc[2][2][4][4] = {};

    const float* Aptr0 = A + (size_t)(m0 + arow) * DMODEL + ak;
    const float* Aptr1 = Aptr0 + (size_t)64 * DMODEL;
    const float* Bptr0 = B + (size_t)brow * DMODEL + n0 + bn;
    const float* Bptr1 = Bptr0 + (size_t)8 * DMODEL;

    float4 av0 = *(const float4*)(Aptr0);
    float4 av1 = *(const float4*)(Aptr1);
    float4 bv0 = *(const float4*)(Bptr0);
    float4 bv1 = *(const float4*)(Bptr1);

    for (int k0 = 0; k0 < DMODEL; k0 += 16) {
        __syncthreads();
        As[ak + 0][arow] = av0.x;  As[ak + 1][arow] = av0.y;
        As[ak + 2][arow] = av0.z;  As[ak + 3][arow] = av0.w;
        As[ak + 0][arow + 64] = av1.x;  As[ak + 1][arow + 64] = av1.y;
        As[ak + 2][arow + 64] = av1.z;  As[ak + 3][arow + 64] = av1.w;
        *(float4*)&Bs[brow][bn]     = bv0;
        *(float4*)&Bs[brow + 8][bn] = bv1;
        __syncthreads();
        if (k0 + 16 < DMODEL) {
            av0 = *(const float4*)(Aptr0 + k0 + 16);
            av1 = *(const float4*)(Aptr1 + k0 + 16);
            bv0 = *(const float4*)(Bptr0 + (size_t)(k0 + 16) * DMODEL);
            bv1 = *(const float4*)(Bptr1 + (size_t)(k0 + 16) * DMODEL);
        }
        #pragma unroll
        for (int kk = 0; kk < 16; ++kk) {
            float4 a0 = *(const float4*)&As[kk][rr];
            float4 a1 = *(const float4*)&As[kk][rr + 64];
            float4 b0 = *(const float4*)&Bs[kk][cc];
            float4 b1 = *(const float4*)&Bs[kk][cc + 64];
            float ar[2][4] = {{a0.x, a0.y, a0.z, a0.w}, {a1.x, a1.y, a1.z, a1.w}};
            float br[2][4] = {{b0.x, b0.y, b0.z, b0.w}, {b1.x, b1.y, b1.z, b1.w}};
            #pragma unroll
            for (int bi = 0; bi < 2; ++bi)
                #pragma unroll
                for (int i = 0; i < 4; ++i)
                    #pragma unroll
                    for (int bj = 0; bj < 2; ++bj)
                        #pragma unroll
                        for (int jj = 0; jj < 4; ++jj)
                            acc[bi][bj][i][jj] += ar[bi][i] * br[bj][jj];
        }
    }

    #pragma unroll
    for (int bi = 0; bi < 2; ++bi)
        #pragma unroll
        for (int i = 0; i < 4; ++i) {
            const size_t row = m0 + bi * 64 + rr + i;
            #pragma unroll
            for (int bj = 0; bj < 2; ++bj) {
                const int col = n0 + bj * 64 + cc;
                *(float4*)&C[row * DMODEL + col] =
                    make_float4(acc[bi][bj][i][0], acc[bi][bj][i][1],
                                acc[bi][bj][i][2], acc[bi][bj][i][3]);
            }
        }
}

// ---------------------------------------------------------------------------
// Launcher. Inputs (setup_inputs order): x, cos, sin, W_q, W_k, W_v, W_out.
// Workspace layout (needs 64 MiB): q | k | v | z, each B*H*T*D floats.
// ---------------------------------------------------------------------------
extern "C" void kernel_launch(void* const* d_in, const int* in_sizes, int n_in,
                              void* d_out, int out_size, void* d_ws, size_t ws_size,
                              hipStream_t stream)
{
    const float* x    = (const float*)d_in[0];
    const float* cosb = (const float*)d_in[1];
    const float* sinb = (const float*)d_in[2];
    const float* Wq   = (const float*)d_in[3];
    const float* Wk   = (const float*)d_in[4];
    const float* Wv   = (const float*)d_in[5];
    const float* Wo   = (const float*)d_in[6];
    float* out = (float*)d_out;

    const size_t per = (size_t)BATCH * NHEADS * TSEQ * DHEAD;  // 4,194,304 floats
    float* q = (float*)d_ws;
    float* k = q + per;
    float* v = k + per;
    float* z = v + per;

    qkv_rope_kernel<<<dim3(24, 32), 256, 0, stream>>>(x, Wq, Wk, Wv, cosb, sinb, q, k, v);
    attn_kernel<<<dim3(32, 32), 256, 0, stream>>>(q, k, v, z);
    out_proj_kernel<<<dim3(8, 32), 256, 0, stream>>>(z, Wo, out);
}

// Round 4
// 584.199 us; speedup vs baseline: 1.7369x; 1.7369x over previous
//
#include <hip/hip_runtime.h>
#include <math.h>

// Problem constants: B=2, T=2048, D_MODEL=1024, H=16, D=64.
#define TSEQ   2048
#define DMODEL 1024
#define NHEADS 16
#define DHEAD  64
#define BATCH  2

typedef __attribute__((ext_vector_type(8))) short short8;   // 8 bf16 (4 VGPRs)
typedef __attribute__((ext_vector_type(4))) float f32x4;    // MFMA C/D

__device__ __forceinline__ unsigned short f2bf(float x) {
    union { float f; unsigned int u; } c; c.f = x;
    unsigned int r = (c.u + 0x7FFFu + ((c.u >> 16) & 1u)) >> 16;   // RNE
    return (unsigned short)r;
}
__device__ __forceinline__ float bf2f(unsigned short h) {
    union { unsigned int u; float f; } c; c.u = ((unsigned int)h) << 16;
    return c.f;
}

// ---------------------------------------------------------------------------
// Kernel 1: fused QKV projection (+RoPE on q,k), fp32 compute, 128x128x16 tile.
// Outputs: q,k as bf16 hi/lo pairs [BH][T][64]; v bf16 TRANSPOSED [BH][64][T].
// ---------------------------------------------------------------------------
__global__ __launch_bounds__(256) void qkv_rope_kernel(
    const float* __restrict__ x,
    const float* __restrict__ Wq, const float* __restrict__ Wk,
    const float* __restrict__ Wv,
    const float* __restrict__ cosb, const float* __restrict__ sinb,
    unsigned short* __restrict__ qhi, unsigned short* __restrict__ qlo,
    unsigned short* __restrict__ khi, unsigned short* __restrict__ klo,
    unsigned short* __restrict__ vto)
{
    __shared__ float As[16][132];
    __shared__ float Bs[16][132];

    const int tid = threadIdx.x;
    const int m0  = blockIdx.y * 128;
    const int n0g = blockIdx.x * 128;
    const int section = n0g >> 10;             // 0=q,1=k,2=v
    const int n0 = n0g & 1023;
    const float* __restrict__ W = (section == 0) ? Wq : (section == 1) ? Wk : Wv;

    const int arow = tid >> 2;                 // 0..63 (and +64)
    const int ak   = (tid & 3) << 2;
    const int brow = tid >> 5;                 // 0..7 (and +8)
    const int bn   = (tid & 31) << 2;

    const int rr = (tid & 15) << 2;
    const int cc = (tid >> 4) << 2;

    float acc[2][2][4][4] = {};

    const float* Aptr0 = x + (size_t)(m0 + arow) * DMODEL + ak;
    const float* Aptr1 = Aptr0 + (size_t)64 * DMODEL;
    const float* Bptr0 = W + (size_t)brow * DMODEL + n0 + bn;
    const float* Bptr1 = Bptr0 + (size_t)8 * DMODEL;

    float4 av0 = *(const float4*)(Aptr0);
    float4 av1 = *(const float4*)(Aptr1);
    float4 bv0 = *(const float4*)(Bptr0);
    float4 bv1 = *(const float4*)(Bptr1);

    for (int k0 = 0; k0 < DMODEL; k0 += 16) {
        __syncthreads();
        As[ak + 0][arow] = av0.x;  As[ak + 1][arow] = av0.y;
        As[ak + 2][arow] = av0.z;  As[ak + 3][arow] = av0.w;
        As[ak + 0][arow + 64] = av1.x;  As[ak + 1][arow + 64] = av1.y;
        As[ak + 2][arow + 64] = av1.z;  As[ak + 3][arow + 64] = av1.w;
        *(float4*)&Bs[brow][bn]     = bv0;
        *(float4*)&Bs[brow + 8][bn] = bv1;
        __syncthreads();
        if (k0 + 16 < DMODEL) {
            av0 = *(const float4*)(Aptr0 + k0 + 16);
            av1 = *(const float4*)(Aptr1 + k0 + 16);
            bv0 = *(const float4*)(Bptr0 + (size_t)(k0 + 16) * DMODEL);
            bv1 = *(const float4*)(Bptr1 + (size_t)(k0 + 16) * DMODEL);
        }
        #pragma unroll
        for (int kk = 0; kk < 16; ++kk) {
            float4 a0 = *(const float4*)&As[kk][rr];
            float4 a1 = *(const float4*)&As[kk][rr + 64];
            float4 b0 = *(const float4*)&Bs[kk][cc];
            float4 b1 = *(const float4*)&Bs[kk][cc + 64];
            float ar[2][4] = {{a0.x, a0.y, a0.z, a0.w}, {a1.x, a1.y, a1.z, a1.w}};
            float br[2][4] = {{b0.x, b0.y, b0.z, b0.w}, {b1.x, b1.y, b1.z, b1.w}};
            #pragma unroll
            for (int bi = 0; bi < 2; ++bi)
                #pragma unroll
                for (int i = 0; i < 4; ++i)
                    #pragma unroll
                    for (int bj = 0; bj < 2; ++bj)
                        #pragma unroll
                        for (int jj = 0; jj < 4; ++jj)
                            acc[bi][bj][i][jj] += ar[bi][i] * br[bj][jj];
        }
    }

    const int b = m0 >> 11;
    #pragma unroll
    for (int bi = 0; bi < 2; ++bi) {
        #pragma unroll
        for (int i = 0; i < 4; ++i) {
            const int t = (m0 + bi * 64 + rr + i) & (TSEQ - 1);
            #pragma unroll
            for (int bj = 0; bj < 2; ++bj) {
                const int n  = n0 + bj * 64 + cc;
                const int h  = n >> 6;
                const int d0 = n & 63;
                float a0 = acc[bi][bj][i][0], a1 = acc[bi][bj][i][1];
                float a2 = acc[bi][bj][i][2], a3 = acc[bi][bj][i][3];
                if (section < 2) {
                    const int p0 = d0 >> 1;
                    float c0v = cosb[t * (DHEAD / 2) + p0];
                    float s0v = sinb[t * (DHEAD / 2) + p0];
                    float c1v = cosb[t * (DHEAD / 2) + p0 + 1];
                    float s1v = sinb[t * (DHEAD / 2) + p0 + 1];
                    float r[4];
                    r[0] = a0 * c0v - a1 * s0v;
                    r[1] = a0 * s0v + a1 * c0v;
                    r[2] = a2 * c1v - a3 * s1v;
                    r[3] = a2 * s1v + a3 * c1v;
                    ushort4 uh, ul;
                    uh.x = f2bf(r[0]); ul.x = f2bf(r[0] - bf2f(uh.x));
                    uh.y = f2bf(r[1]); ul.y = f2bf(r[1] - bf2f(uh.y));
                    uh.z = f2bf(r[2]); ul.z = f2bf(r[2] - bf2f(uh.z));
                    uh.w = f2bf(r[3]); ul.w = f2bf(r[3] - bf2f(uh.w));
                    unsigned short* ph = (section == 0) ? qhi : khi;
                    unsigned short* pl = (section == 0) ? qlo : klo;
                    const size_t off = (((size_t)b * NHEADS + h) * TSEQ + t) * DHEAD + d0;
                    *(ushort4*)&ph[off] = uh;
                    *(ushort4*)&pl[off] = ul;
                } else {
                    // v transposed: [BH][64 d][T]
                    const size_t base = ((size_t)b * NHEADS + h) * DHEAD;
                    vto[(base + d0 + 0) * TSEQ + t] = f2bf(a0);
                    vto[(base + d0 + 1) * TSEQ + t] = f2bf(a1);
                    vto[(base + d0 + 2) * TSEQ + t] = f2bf(a2);
                    vto[(base + d0 + 3) * TSEQ + t] = f2bf(a3);
                }
            }
        }
    }
}

// ---------------------------------------------------------------------------
// Kernel 2: causal flash attention, bf16 MFMA 16x16x32, split-precision QK^T.
// Block = 256 thr = 4 waves; wave owns a 16-row q strip of a 64-row q tile.
// Blocks paired (qt, 31-qt): grid (16, 32) -> 512 blocks, 33 KV-tiles each.
// LDS 48KB: Qhi Qlo Khi Klo V P, 64x64 bf16 tiles, XOR chunk swizzle (G4).
// Fragment maps (m89): A row=lane&15,k=(lane>>4)*8+j; B col=lane&15,same k;
// C col=lane&15, row=(lane>>4)*4+reg.
// ---------------------------------------------------------------------------
#define LDSOFF(r, c) (((r) << 7) + ((((c) ^ ((r) & 7))) << 4))

__device__ __forceinline__ void stage64x64(const unsigned short* __restrict__ g,
                                           int rs_elems, char* lbase, int tid) {
    const int r = tid >> 3;          // 0..31 (+32)
    const int c = tid & 7;           // 16B chunk in row
    const char* gb = (const char*)g;
    uint4 v0 = *(const uint4*)(gb + (size_t)r * rs_elems * 2 + (c << 4));
    uint4 v1 = *(const uint4*)(gb + (size_t)(r + 32) * rs_elems * 2 + (c << 4));
    *(uint4*)(lbase + LDSOFF(r, c)) = v0;
    *(uint4*)(lbase + LDSOFF(r + 32, c)) = v1;
}

__device__ __forceinline__ short8 frag(const char* lbase, int row, int chunk) {
    union { uint4 u; short8 s; } cv;
    cv.u = *(const uint4*)(lbase + LDSOFF(row, chunk));
    return cv.s;
}

__global__ __launch_bounds__(256) void attn_mfma_kernel(
    const unsigned short* __restrict__ qhig, const unsigned short* __restrict__ qlog,
    const unsigned short* __restrict__ khig, const unsigned short* __restrict__ klog,
    const unsigned short* __restrict__ vtg, float* __restrict__ z)
{
    __shared__ __align__(16) char smem[49152];
    char* Qhb = smem;                 // 8KB each
    char* Qlb = smem + 8192;
    char* Khb = smem + 16384;
    char* Klb = smem + 24576;
    char* Vb  = smem + 32768;
    char* Pb  = smem + 40960;

    const int tid  = threadIdx.x;
    const int lane = tid & 63;
    const int wave = tid >> 6;
    const int ln15 = lane & 15;
    const int g    = lane >> 4;

    const int bh = blockIdx.y;
    const int b  = bh >> 4;
    const int h  = bh & 15;
    const unsigned short* qhh = qhig + (size_t)bh * TSEQ * DHEAD;
    const unsigned short* qlh = qlog + (size_t)bh * TSEQ * DHEAD;
    const unsigned short* khh = khig + (size_t)bh * TSEQ * DHEAD;
    const unsigned short* klh = klog + (size_t)bh * TSEQ * DHEAD;
    const unsigned short* vth = vtg  + (size_t)bh * DHEAD * TSEQ;

    for (int half = 0; half < 2; ++half) {
        const int qt = half ? (31 - (int)blockIdx.x) : (int)blockIdx.x;

        __syncthreads();                        // protect Q LDS from previous half
        stage64x64(qhh + (size_t)qt * 64 * DHEAD, DHEAD, Qhb, tid);
        stage64x64(qlh + (size_t)qt * 64 * DHEAD, DHEAD, Qlb, tid);
        __syncthreads();                        // Q visible to all waves

        // hoist loop-invariant Q fragments (A operand, row rA within strip)
        const int rA = 16 * wave + ln15;
        short8 qh0 = frag(Qhb, rA, g),     qh1 = frag(Qhb, rA, 4 + g);
        short8 ql0 = frag(Qlb, rA, g),     ql1 = frag(Qlb, rA, 4 + g);

        float m_i[4], l_i[4];
        f32x4 oacc[4];
        #pragma unroll
        for (int i2 = 0; i2 < 4; ++i2) {
            m_i[i2] = -INFINITY; l_i[i2] = 0.f;
            oacc[i2][0] = 0.f; oacc[i2][1] = 0.f; oacc[i2][2] = 0.f; oacc[i2][3] = 0.f;
        }

        for (int jt = 0; jt <= qt; ++jt) {
            __syncthreads();                    // prior tile reads of K/V/P done
            stage64x64(khh + (size_t)jt * 64 * DHEAD, DHEAD, Khb, tid);
            stage64x64(klh + (size_t)jt * 64 * DHEAD, DHEAD, Klb, tid);
            stage64x64(vth + (size_t)jt * 64, TSEQ, Vb, tid);
            __syncthreads();

            // ---- S = Q K^T (strip 16 x 64), split-precision ----
            f32x4 sacc[4];
            #pragma unroll
            for (int ct = 0; ct < 4; ++ct) {
                const int rB = ct * 16 + ln15;
                short8 kh0 = frag(Khb, rB, g), kh1 = frag(Khb, rB, 4 + g);
                short8 kl0 = frag(Klb, rB, g), kl1 = frag(Klb, rB, 4 + g);
                f32x4 acc = {0.f, 0.f, 0.f, 0.f};
                acc = __builtin_amdgcn_mfma_f32_16x16x32_bf16(qh0, kh0, acc, 0, 0, 0);
                acc = __builtin_amdgcn_mfma_f32_16x16x32_bf16(qh1, kh1, acc, 0, 0, 0);
                acc = __builtin_amdgcn_mfma_f32_16x16x32_bf16(qh0, kl0, acc, 0, 0, 0);
                acc = __builtin_amdgcn_mfma_f32_16x16x32_bf16(qh1, kl1, acc, 0, 0, 0);
                acc = __builtin_amdgcn_mfma_f32_16x16x32_bf16(ql0, kh0, acc, 0, 0, 0);
                acc = __builtin_amdgcn_mfma_f32_16x16x32_bf16(ql1, kh1, acc, 0, 0, 0);
                sacc[ct] = acc;
            }

            // ---- online softmax (rows = 16*wave + 4*g + reg) ----
            const bool diag = (jt == qt);
            #pragma unroll
            for (int reg = 0; reg < 4; ++reg) {
                const int rloc = 16 * wave + 4 * g + reg;    // local q row 0..63
                float sv[4];
                #pragma unroll
                for (int ct = 0; ct < 4; ++ct) {
                    float xv = sacc[ct][reg] * 0.125f;       // 1/sqrt(64)
                    if (diag && (ct * 16 + ln15 > rloc)) xv = -INFINITY;
                    sv[ct] = xv;
                }
                float mr = fmaxf(fmaxf(sv[0], sv[1]), fmaxf(sv[2], sv[3]));
                #pragma unroll
                for (int off = 1; off < 16; off <<= 1)
                    mr = fmaxf(mr, __shfl_xor(mr, off));
                float mnew = fmaxf(m_i[reg], mr);
                float al   = __expf(m_i[reg] - mnew);        // exp(-inf)=0 first tile
                float rs = 0.f;
                unsigned short pb[4];
                #pragma unroll
                for (int ct = 0; ct < 4; ++ct) {
                    float p = __expf(sv[ct] - mnew);
                    pb[ct] = f2bf(p);
                    rs += bf2f(pb[ct]);          // consistent with PV numerator
                }
                #pragma unroll
                for (int off = 1; off < 16; off <<= 1)
                    rs += __shfl_xor(rs, off);
                l_i[reg] = l_i[reg] * al + rs;
                m_i[reg] = mnew;
                #pragma unroll
                for (int dt = 0; dt < 4; ++dt)
                    oacc[dt][reg] *= al;
                // write P rows owned by this wave only -> intra-wave, no barrier
                #pragma unroll
                for (int ct = 0; ct < 4; ++ct) {
                    const int col = ct * 16 + ln15;
                    const int chunk = col >> 3;
                    const int byt = (rloc << 7) + ((chunk ^ (rloc & 7)) << 4) + ((col & 7) << 1);
                    *(unsigned short*)(Pb + byt) = pb[ct];
                }
            }

            // ---- O += P V  (A = P own strip; B = Vt[d][k] tile) ----
            short8 pa0 = frag(Pb, rA, g);
            short8 pa1 = frag(Pb, rA, 4 + g);
            #pragma unroll
            for (int dt = 0; dt < 4; ++dt) {
                short8 vb0 = frag(Vb, dt * 16 + ln15, g);
                short8 vb1 = frag(Vb, dt * 16 + ln15, 4 + g);
                oacc[dt] = __builtin_amdgcn_mfma_f32_16x16x32_bf16(pa0, vb0, oacc[dt], 0, 0, 0);
                oacc[dt] = __builtin_amdgcn_mfma_f32_16x16x32_bf16(pa1, vb1, oacc[dt], 0, 0, 0);
            }
        }

        // ---- epilogue: z[b][t][h*64 + d] fp32 ----
        #pragma unroll
        for (int reg = 0; reg < 4; ++reg) {
            const float inv = 1.0f / l_i[reg];
            const int t = qt * 64 + 16 * wave + 4 * g + reg;
            float* zrow = z + ((size_t)(b * TSEQ + t)) * DMODEL + h * DHEAD;
            #pragma unroll
            for (int dt = 0; dt < 4; ++dt)
                zrow[dt * 16 + ln15] = oacc[dt][reg] * inv;
        }
    }
}

// ---------------------------------------------------------------------------
// Kernel 3: output projection z @ W_out -> out. fp32 128x128x16 GEMM.
// ---------------------------------------------------------------------------
__global__ __launch_bounds__(256) void out_proj_kernel(
    const float* __restrict__ A, const float* __restrict__ B,
    float* __restrict__ C)
{
    __shared__ float As[16][132];
    __shared__ float Bs[16][132];

    const int tid = threadIdx.x;
    const int m0 = blockIdx.y * 128;
    const int n0 = blockIdx.x * 128;

    const int arow = tid >> 2;
    const int ak   = (tid & 3) << 2;
    const int brow = tid >> 5;
    const int bn   = (tid & 31) << 2;
    const int rr   = (tid & 15) << 2;
    const int cc   = (tid >> 4) << 2;

    float acc[2][2][4][4] = {};

    const float* Aptr0 = A + (size_t)(m0 + arow) * DMODEL + ak;
    const float* Aptr1 = Aptr0 + (size_t)64 * DMODEL;
    const float* Bptr0 = B + (size_t)brow * DMODEL + n0 + bn;
    const float* Bptr1 = Bptr0 + (size_t)8 * DMODEL;

    float4 av0 = *(const float4*)(Aptr0);
    float4 av1 = *(const float4*)(Aptr1);
    float4 bv0 = *(const float4*)(Bptr0);
    float4 bv1 = *(const float4*)(Bptr1);

    for (int k0 = 0; k0 < DMODEL; k0 += 16) {
        __syncthreads();
        As[ak + 0][arow] = av0.x;  As[ak + 1][arow] = av0.y;
        As[ak + 2][arow] = av0.z;  As[ak + 3][arow] = av0.w;
        As[ak + 0][arow + 64] = av1.x;  As[ak + 1][arow + 64] = av1.y;
        As[ak + 2][arow + 64] = av1.z;  As[ak + 3][arow + 64] = av1.w;
        *(float4*)&Bs[brow][bn]     = bv0;
        *(float4*)&Bs[brow + 8][bn] = bv1;
        __syncthreads();
        if (k0 + 16 < DMODEL) {
            av0 = *(const float4*)(Aptr0 + k0 + 16);
            av1 = *(const float4*)(Aptr1 + k0 + 16);
            bv0 = *(const float4*)(Bptr0 + (size_t)(k0 + 16) * DMODEL);
            bv1 = *(const float4*)(Bptr1 + (size_t)(k0 + 16) * DMODEL);
        }
        #pragma unroll
        for (int kk = 0; kk < 16; ++kk) {
            float4 a0 = *(const float4*)&As[kk][rr];
            float4 a1 = *(const float4*)&As[kk][rr + 64];
            float4 b0 = *(const float4*)&Bs[kk][cc];
            float4 b1 = *(const float4*)&Bs[kk][cc + 64];
            float ar[2][4] = {{a0.x, a0.y, a0.z, a0.w}, {a1.x, a1.y, a1.z, a1.w}};
            float br[2][4] = {{b0.x, b0.y, b0.z, b0.w}, {b1.x, b1.y, b1.z, b1.w}};
            #pragma unroll
            for (int bi = 0; bi < 2; ++bi)
                #pragma unroll
                for (int i = 0; i < 4; ++i)
                    #pragma unroll
                    for (int bj = 0; bj < 2; ++bj)
                        #pragma unroll
                        for (int jj = 0; jj < 4; ++jj)
                            acc[bi][bj][i][jj] += ar[bi][i] * br[bj][jj];
        }
    }

    #pragma unroll
    for (int bi = 0; bi < 2; ++bi)
        #pragma unroll
        for (int i = 0; i < 4; ++i) {
            const size_t row = m0 + bi * 64 + rr + i;
            #pragma unroll
            for (int bj = 0; bj < 2; ++bj) {
                const int col = n0 + bj * 64 + cc;
                *(float4*)&C[row * DMODEL + col] =
                    make_float4(acc[bi][bj][i][0], acc[bi][bj][i][1],
                                acc[bi][bj][i][2], acc[bi][bj][i][3]);
            }
        }
}

// ---------------------------------------------------------------------------
// Launcher. ws layout: qhi|qlo|khi|klo|vT (8MB bf16 each) | z (16MB f32) = 56MB.
// ---------------------------------------------------------------------------
extern "C" void kernel_launch(void* const* d_in, const int* in_sizes, int n_in,
                              void* d_out, int out_size, void* d_ws, size_t ws_size,
                              hipStream_t stream)
{
    const float* x    = (const float*)d_in[0];
    const float* cosb = (const float*)d_in[1];
    const float* sinb = (const float*)d_in[2];
    const float* Wq   = (const float*)d_in[3];
    const float* Wk   = (const float*)d_in[4];
    const float* Wv   = (const float*)d_in[5];
    const float* Wo   = (const float*)d_in[6];
    float* out = (float*)d_out;

    const size_t per = (size_t)BATCH * NHEADS * TSEQ * DHEAD;  // 4,194,304
    unsigned short* qhi = (unsigned short*)d_ws;
    unsigned short* qlo = qhi + per;
    unsigned short* khi = qlo + per;
    unsigned short* klo = khi + per;
    unsigned short* vt  = klo + per;
    float* z = (float*)(vt + per);

    qkv_rope_kernel<<<dim3(24, 32), 256, 0, stream>>>(x, Wq, Wk, Wv, cosb, sinb,
                                                      qhi, qlo, khi, klo, vt);
    attn_mfma_kernel<<<dim3(16, 32), 256, 0, stream>>>(qhi, qlo, khi, klo, vt, z);
    out_proj_kernel<<<dim3(8, 32), 256, 0, stream>>>(z, Wo, out);
}